// Round 19
// baseline (370.729 us; speedup 1.0000x reference)
//
#include <hip/hip_runtime.h>
#include <hip/hip_bf16.h>
#include <stdint.h>

// MoE: T=4096 tokens, D_MODEL=1024, D_FF=4096, E=8, top-2.
// R19: r17 (best 367.4us) + software-pipelined 4-tile transpose blocks
//      (tile s+1 loads issued before tile s convert/LDS/store: hides HBM
//      latency inside a block; 4x fewer block launches).

#define T_TOK 4096
#define DM 1024
#define DF 4096
#define NE 8
#define BM 128              // M tile (pair rows)
#define BN 128              // N tile
#define BK 64               // K step
#define MAX_TILES 72        // sum ceil(c_e/128) <= 64 + 8
#define PAIR_CAP 9216       // MAX_TILES * 128
#define G1_GRID (MAX_TILES * 32)     // 2304 gemm1 work slots
#define TSTR 138            // transpose LDS stride (ushorts)

typedef __bf16 bf16x8 __attribute__((ext_vector_type(8)));
typedef float f32x4 __attribute__((ext_vector_type(4)));
typedef unsigned short ushort_t;

__device__ __forceinline__ ushort_t f2bf(float f) {
  uint32_t u = __float_as_uint(f);
  u += 0x7FFFu + ((u >> 16) & 1u);   // RNE
  return (ushort_t)(u >> 16);
}

// ---- workspace layout (bytes) ----
#define W1T_OFF 0ull                 // [E][DF][DM] bf16 = 64MiB
#define W2T_OFF 67108864ull          // [E][DM][DF] bf16 = 64MiB
#define XB_OFF  134217728ull         // [T][DM] bf16 = 8MiB
#define H_OFF   142606336ull         // [PAIR_CAP][DF] bf16 = 72MiB
#define RT_OFF  218103808ull         // routing block
#define RO_COUNTS   0
#define RO_NTILES   96
#define RO_TILE_E   128              // 288B
#define RO_TILE_S   448              // 288B
#define RO_TILE_R   768              // 288B
#define RO_PTOK     1088             // 36864B
#define RO_PW       37952            // 36864B
#define RO_TOPI     74816            // 32768B
#define RO_TOPW     107584           // 32768B
#define RT_BYTES    140352ull
#define WS_NEEDED   (RT_OFF + RT_BYTES)

// Runtime-balanced XCD-chunked mapping (XCD of block b = b%8).
__device__ __forceinline__ int xcd_work(int b, int live) {
  int k = b & 7, j = b >> 3;
  int q = live >> 3, r = live & 7;
  int cnt = q + (k < r ? 1 : 0);
  if (j >= cnt) return -1;
  int start = k * q + (k < r ? k : r);
  return start + j;
}

// ------------------------------------------------------------------
// Pipelined 4-tile transpose body. Tiles t4..t4+3 (consecutive bx =>
// adjacent 256B column slices of the same 128-row band). Loads for the
// next tile are issued BEFORE the current tile's convert/LDS/store.
// W1 decode: bx = t&63, by = (t>>6)&7, e = t>>9  (R=DM, C=DF)
// W2 decode: bx = t&15, by = (t>>4)&31, e = t>>9 (R=DF, C=DM)
// ------------------------------------------------------------------
#define TP_LOAD(dstv, t_, src_, R_, C_, BXM_, BYS_)                            \
  {                                                                            \
    int e_ = (t_) >> 9, t2_ = (t_) & 511;                                      \
    int bx_ = t2_ & (BXM_), by_ = t2_ >> (BYS_);                               \
    const float* s_ = (src_) + (size_t)e_ * (R_) * (C_) +                      \
                      (size_t)(by_ * 128) * (C_) + bx_ * 64;                   \
    _Pragma("unroll")                                                          \
    for (int i_ = 0; i_ < 8; ++i_)                                             \
      dstv[i_] = *(const float4*)&s_[(size_t)(i_ * 16 + tr) * (C_) + tc];      \
  }

#define TP_FLUSH(srcv, t_, dst_, R_, C_, BXM_, BYS_)                           \
  {                                                                            \
    int e_ = (t_) >> 9, t2_ = (t_) & 511;                                      \
    int bx_ = t2_ & (BXM_), by_ = t2_ >> (BYS_);                               \
    _Pragma("unroll")                                                          \
    for (int i_ = 0; i_ < 8; ++i_) {                                           \
      int r_ = i_ * 16 + tr;                                                   \
      sh[(tc + 0) * TSTR + r_] = f2bf(srcv[i_].x);                             \
      sh[(tc + 1) * TSTR + r_] = f2bf(srcv[i_].y);                             \
      sh[(tc + 2) * TSTR + r_] = f2bf(srcv[i_].z);                             \
      sh[(tc + 3) * TSTR + r_] = f2bf(srcv[i_].w);                             \
    }                                                                          \
    __syncthreads();                                                           \
    ushort_t* d_ = (dst_) + (size_t)e_ * (R_) * (C_) +                         \
                   (size_t)(bx_ * 64) * (R_) + by_ * 128;                      \
    _Pragma("unroll")                                                          \
    for (int j_ = 0; j_ < 8; ++j_) {                                           \
      int c_ = j_ * 8 + cr;                                                    \
      ushort4 o_ = { sh[c_ * TSTR + rg], sh[c_ * TSTR + rg + 1],               \
                     sh[c_ * TSTR + rg + 2], sh[c_ * TSTR + rg + 3] };         \
      *(ushort4*)&d_[(size_t)c_ * (R_) + rg] = o_;                             \
    }                                                                          \
    __syncthreads();                                                           \
  }

#define TP_PIPE4(t4_, src_, dst_, R_, C_, BXM_, BYS_)                          \
  {                                                                            \
    int tr = threadIdx.x >> 4, tc = (threadIdx.x & 15) << 2;                   \
    int cr = threadIdx.x >> 5, rg = (threadIdx.x & 31) << 2;                   \
    float4 va[8], vb[8];                                                       \
    TP_LOAD(va, (t4_), src_, R_, C_, BXM_, BYS_);                              \
    TP_LOAD(vb, (t4_) + 1, src_, R_, C_, BXM_, BYS_);                          \
    TP_FLUSH(va, (t4_), dst_, R_, C_, BXM_, BYS_);                             \
    TP_LOAD(va, (t4_) + 2, src_, R_, C_, BXM_, BYS_);                          \
    TP_FLUSH(vb, (t4_) + 1, dst_, R_, C_, BXM_, BYS_);                         \
    TP_LOAD(vb, (t4_) + 3, src_, R_, C_, BXM_, BYS_);                          \
    TP_FLUSH(va, (t4_) + 2, dst_, R_, C_, BXM_, BYS_);                         \
    TP_FLUSH(vb, (t4_) + 3, dst_, R_, C_, BXM_, BYS_);                         \
  }

// ------------------------------------------------------------------
// 1. Fused: gate (+x->bf16) blocks [0,1024) ∥ w1-transpose blocks
//    [1024,2048), each transposing 4 tiles pipelined.
// ------------------------------------------------------------------
__global__ __launch_bounds__(256) void gate_w1t_kernel(
    const float* __restrict__ x, const float* __restrict__ gw,
    int* __restrict__ counts, int* __restrict__ topi,
    float* __restrict__ topw, ushort_t* __restrict__ xb,
    const float* __restrict__ w1, ushort_t* __restrict__ w1t) {
  __shared__ ushort_t sh[64 * TSTR];
  int b = blockIdx.x;
  if (b >= 1024) {
    int t4 = (b - 1024) * 4;          // 1024 blocks x 4 tiles = 4096
    TP_PIPE4(t4, w1, w1t, DM, DF, 63, 6);
    return;
  }
  int wave = threadIdx.x >> 6;
  int lane = threadIdx.x & 63;
  int t = b * 4 + wave;
  const float* xr = x + (size_t)t * DM;
  ushort_t* xbr = xb + (size_t)t * DM;
  float acc[NE];
#pragma unroll
  for (int e = 0; e < NE; ++e) acc[e] = 0.f;
#pragma unroll
  for (int it = 0; it < DM / 256; ++it) {
    int d0 = (it * 64 + lane) * 4;
    float4 v = *(const float4*)&xr[d0];
    ushort4 o = { f2bf(v.x), f2bf(v.y), f2bf(v.z), f2bf(v.w) };
    *(ushort4*)&xbr[d0] = o;
    const float* g0 = gw + (size_t)d0 * NE;
#pragma unroll
    for (int e = 0; e < NE; ++e)
      acc[e] += v.x * g0[e] + v.y * g0[NE + e] + v.z * g0[2 * NE + e] + v.w * g0[3 * NE + e];
  }
#pragma unroll
  for (int off = 32; off > 0; off >>= 1) {
#pragma unroll
    for (int e = 0; e < NE; ++e) acc[e] += __shfl_xor(acc[e], off, 64);
  }
  if (lane == 0) {
    int i0 = 0; float v0 = acc[0];
#pragma unroll
    for (int e = 1; e < NE; ++e) if (acc[e] > v0) { v0 = acc[e]; i0 = e; }
    int i1 = -1; float v1 = -1e30f;
#pragma unroll
    for (int e = 0; e < NE; ++e) if (e != i0 && acc[e] > v1) { v1 = acc[e]; i1 = e; }
    float e1 = expf(v1 - v0);
    float w0 = 1.f / (1.f + e1);
    float w1s = e1 / (1.f + e1);
    topi[t * 2] = i0; topi[t * 2 + 1] = i1;
    topw[t * 2] = w0; topw[t * 2 + 1] = w1s;
    atomicAdd(&counts[i0], 1);
    atomicAdd(&counts[i1], 1);
  }
}

// ------------------------------------------------------------------
// 2. Route: scan (thread 0) + parallel scatter, one block, LDS cursors
// ------------------------------------------------------------------
__global__ void route_kernel(const int* __restrict__ counts,
                             const int* __restrict__ topi, const float* __restrict__ topw,
                             int* __restrict__ n_tiles, int* __restrict__ tile_e,
                             int* __restrict__ tile_s, int* __restrict__ tile_r,
                             int* __restrict__ ptok, float* __restrict__ pw) {
  __shared__ int loff[NE];
  __shared__ int lcur[NE];
  if (threadIdx.x == 0) {
    int off = 0, nt = 0;
    for (int e = 0; e < NE; ++e) {
      loff[e] = off;
      lcur[e] = 0;
      int c = counts[e];
      for (int m0 = 0; m0 < c; m0 += BM) {
        tile_e[nt] = e;
        tile_s[nt] = off + m0;
        tile_r[nt] = (c - m0 < BM) ? (c - m0) : BM;
        ++nt;
      }
      off += ((c + BM - 1) / BM) * BM;
    }
    *n_tiles = nt;
  }
  __syncthreads();
  for (int t = threadIdx.x; t < T_TOK; t += 256) {
#pragma unroll
    for (int k = 0; k < 2; ++k) {
      int e = topi[t * 2 + k];
      int pos = atomicAdd(&lcur[e], 1);
      int p = loff[e] + pos;
      ptok[p] = t;
      pw[p] = topw[t * 2 + k];
    }
  }
}

// ==================================================================
// m97-replica 128x128xBK64 grouped-GEMM core (unchanged).
// ==================================================================

#define GLD(srcp, dstp)                                                        \
  __builtin_amdgcn_global_load_lds(                                            \
      (const __attribute__((address_space(1))) void*)(srcp),                   \
      (__attribute__((address_space(3))) void*)(dstp), 16, 0, 0)

__device__ __forceinline__ void gemm_core(
    ushort_t* As, ushort_t* Bs,
    const ushort_t* const (&a_sp)[4], const ushort_t* const (&b_sp)[4],
    int NT, int wid, int lane, f32x4 (&acc)[4][4]) {
  int fr = lane & 15, ch = lane >> 4, sw = lane & 7;
  int k0s = (ch ^ sw) * 8;
  int k1s = ((ch + 4) ^ sw) * 8;
  int m_off = (wid >> 1) * 64, n_off = (wid & 1) * 64;
  int abase = (m_off + fr) * 64;
  int bbase = (n_off + fr) * 64;

  for (int t = 0; t < NT; ++t) {
    int k0 = t * BK;
#pragma unroll
    for (int j = 0; j < 4; ++j) {
      GLD(a_sp[j] + k0, As + (wid * 4 + j) * 512);
      GLD(b_sp[j] + k0, Bs + (wid * 4 + j) * 512);
    }
    asm volatile("s_waitcnt vmcnt(0)" ::: "memory");
    __syncthreads();

#pragma unroll
    for (int kx = 0; kx < 2; ++kx) {
      int ks = kx ? k1s : k0s;
      bf16x8 af[4], bf[4];
#pragma unroll
      for (int mi = 0; mi < 4; ++mi) af[mi] = *(const bf16x8*)&As[abase + mi * 1024 + ks];
#pragma unroll
      for (int ni = 0; ni < 4; ++ni) bf[ni] = *(const bf16x8*)&Bs[bbase + ni * 1024 + ks];
#pragma unroll
      for (int mi = 0; mi < 4; ++mi)
#pragma unroll
        for (int ni = 0; ni < 4; ++ni)
          acc[mi][ni] = __builtin_amdgcn_mfma_f32_16x16x32_bf16(af[mi], bf[ni], acc[mi][ni], 0, 0, 0);
    }
    __syncthreads();
  }
}

// ------------------------------------------------------------------
// 3. Fused: gemm1 blocks [0,G1_GRID) ∥ w2-transpose blocks
//    [G1_GRID, G1_GRID+1024), each transposing 4 tiles pipelined.
// ------------------------------------------------------------------
__global__ __launch_bounds__(256, 4) void gemm1_w2t_kernel(
    const ushort_t* __restrict__ xb, const ushort_t* __restrict__ w1t,
    ushort_t* __restrict__ h,
    const int* __restrict__ n_tiles, const int* __restrict__ tile_e,
    const int* __restrict__ tile_s, const int* __restrict__ tile_r,
    const int* __restrict__ ptok,
    const float* __restrict__ w2, ushort_t* __restrict__ w2t) {
  __shared__ ushort_t sh[BM * BK + BN * BK];   // 32 KiB; transpose uses 64*138
  int b = blockIdx.x;
  if (b >= G1_GRID) {
    int t4 = (b - G1_GRID) * 4;       // 1024 blocks x 4 tiles = 4096
    TP_PIPE4(t4, w2, w2t, DF, DM, 15, 4);
    return;
  }
  int nt = *n_tiles;
  int ntp = (nt + 3) & ~3;
  int w = xcd_work(b, ntp * 32);
  if (w < 0) return;
  int g = w >> 5, r = w & 31;
  int tg = g >> 2, ng = g & 3;
  int tile = tg * 4 + (r & 3);
  if (tile >= nt) return;
  int n0 = (ng * 8 + (r >> 2)) * BN;
  int e = tile_e[tile], p0 = tile_s[tile], rows = tile_r[tile];

  ushort_t* As = sh;
  ushort_t* Bs = sh + BM * BK;
  int tid = threadIdx.x, wid = tid >> 6, lane = tid & 63;
  int lr = lane >> 3;
  int swc = (lane & 7) ^ (lr & 7);

  const ushort_t* a_sp[4];
  const ushort_t* b_sp[4];
#pragma unroll
  for (int j = 0; j < 4; ++j) {
    int rr = wid * 32 + j * 8 + lr;
    int tok = (rr < rows) ? ptok[p0 + rr] : 0;
    a_sp[j] = xb + (size_t)tok * DM + swc * 8;
    b_sp[j] = w1t + ((size_t)e * DF + n0 + rr) * DM + swc * 8;
  }

  f32x4 acc[4][4] = {};
  gemm_core(As, Bs, a_sp, b_sp, DM / BK, wid, lane, acc);

  int m_off = (wid >> 1) * 64, n_off = (wid & 1) * 64;
  int col = lane & 15, rq = (lane >> 4) * 4;
#pragma unroll
  for (int mi = 0; mi < 4; ++mi)
#pragma unroll
    for (int rr = 0; rr < 4; ++rr) {
      int m = m_off + mi * 16 + rq + rr;
      bool valid = m < rows;
      size_t rowoff = (size_t)(p0 + m) * DF + n0 + n_off;
#pragma unroll
      for (int ni = 0; ni < 4; ++ni) {
        float v = acc[mi][ni][rr];
        v = valid ? (v > 0.f ? v : 0.f) : 0.f;
        h[rowoff + ni * 16 + col] = f2bf(v);
      }
    }
}

// ------------------------------------------------------------------
// 4. GEMM2: out[tok(p)] += pw[p] * (h[p] @ W2_e)   (atomic epilogue,
//    2 commutative adds/element -> deterministic). Supertile 2x2.
// ------------------------------------------------------------------
__global__ __launch_bounds__(256, 4) void gemm2_kernel(
    const ushort_t* __restrict__ h, const ushort_t* __restrict__ w2t,
    float* __restrict__ out,
    const int* __restrict__ n_tiles, const int* __restrict__ tile_e,
    const int* __restrict__ tile_s, const int* __restrict__ tile_r,
    const int* __restrict__ ptok, const float* __restrict__ pw) {
  int nt = *n_tiles;
  int ntp = (nt + 1) & ~1;
  int w = xcd_work(blockIdx.x, ntp * 8);
  if (w < 0) return;
  int g = w >> 2, r = w & 3;
  int tg = g >> 2, ng = g & 3;
  int tile = tg * 2 + (r & 1);
  if (tile >= nt) return;
  int n0 = (ng * 2 + (r >> 1)) * BN;
  int e = tile_e[tile], p0 = tile_s[tile], rows = tile_r[tile];

  __shared__ ushort_t As[BM * BK];
  __shared__ ushort_t Bs[BN * BK];
  int tid = threadIdx.x, wid = tid >> 6, lane = tid & 63;
  int lr = lane >> 3;
  int swc = (lane & 7) ^ (lr & 7);

  const ushort_t* a_sp[4];
  const ushort_t* b_sp[4];
#pragma unroll
  for (int j = 0; j < 4; ++j) {
    int rr = wid * 32 + j * 8 + lr;
    a_sp[j] = h + (size_t)(p0 + rr) * DF + swc * 8;
    b_sp[j] = w2t + ((size_t)e * DM + n0 + rr) * DF + swc * 8;
  }

  f32x4 acc[4][4] = {};
  gemm_core(As, Bs, a_sp, b_sp, DF / BK, wid, lane, acc);

  int m_off = (wid >> 1) * 64, n_off = (wid & 1) * 64;
  int col = lane & 15, rq = (lane >> 4) * 4;
#pragma unroll
  for (int mi = 0; mi < 4; ++mi)
#pragma unroll
    for (int rr = 0; rr < 4; ++rr) {
      int m = m_off + mi * 16 + rq + rr;
      if (m < rows) {
        int p = p0 + m;
        int tok = ptok[p];
        float wgt = pw[p];
        size_t o = (size_t)tok * DM + n0 + n_off;
#pragma unroll
        for (int ni = 0; ni < 4; ++ni)
          atomicAdd(&out[o + ni * 16 + col], wgt * acc[mi][ni][rr]);
      }
    }
}

// ------------------------------------------------------------------
extern "C" void kernel_launch(void* const* d_in, const int* in_sizes, int n_in,
                              void* d_out, int out_size, void* d_ws, size_t ws_size,
                              hipStream_t stream) {
  const float* x  = (const float*)d_in[0];   // [2,2048,1024]
  const float* gw = (const float*)d_in[1];   // [1024,8]
  const float* w1 = (const float*)d_in[2];   // [8,1024,4096]
  const float* w2 = (const float*)d_in[3];   // [8,4096,1024]
  float* out = (float*)d_out;                // [4096,1024]
  char* ws = (char*)d_ws;
  if (ws_size < WS_NEEDED) return;

  ushort_t* w1t = (ushort_t*)(ws + W1T_OFF);
  ushort_t* w2t = (ushort_t*)(ws + W2T_OFF);
  ushort_t* xb  = (ushort_t*)(ws + XB_OFF);
  ushort_t* h   = (ushort_t*)(ws + H_OFF);
  char* rt = ws + RT_OFF;
  int*   counts  = (int*)(rt + RO_COUNTS);
  int*   n_tiles = (int*)(rt + RO_NTILES);
  int*   tile_e  = (int*)(rt + RO_TILE_E);
  int*   tile_s  = (int*)(rt + RO_TILE_S);
  int*   tile_r  = (int*)(rt + RO_TILE_R);
  int*   ptok    = (int*)(rt + RO_PTOK);
  float* pw      = (float*)(rt + RO_PW);
  int*   topi    = (int*)(rt + RO_TOPI);
  float* topw    = (float*)(rt + RO_TOPW);

  hipMemsetAsync(rt, 0, 128, stream);
  hipMemsetAsync(out, 0, (size_t)T_TOK * DM * sizeof(float), stream);

  hipLaunchKernelGGL(gate_w1t_kernel, dim3(1024 + 1024), dim3(256), 0, stream,
                     x, gw, counts, topi, topw, xb, w1, w1t);
  hipLaunchKernelGGL(route_kernel, dim3(1), dim3(256), 0, stream,
                     counts, topi, topw, n_tiles, tile_e, tile_s, tile_r, ptok, pw);
  hipLaunchKernelGGL(gemm1_w2t_kernel, dim3(G1_GRID + 1024), dim3(256), 0, stream,
                     xb, w1t, h, n_tiles, tile_e, tile_s, tile_r, ptok, w2, w2t);
  hipLaunchKernelGGL(gemm2_kernel, dim3(MAX_TILES * 8), dim3(256), 0, stream,
                     h, w2t, out, n_tiles, tile_e, tile_s, tile_r, ptok, pw);
}

// Round 20
// 358.077 us; speedup vs baseline: 1.0353x; 1.0353x over previous
//
#include <hip/hip_runtime.h>
#include <hip/hip_bf16.h>
#include <stdint.h>

// MoE: T=4096 tokens, D_MODEL=1024, D_FF=4096, E=8, top-2.
// R20: r17 (best 367.4us) + INTERLEAVED block types in k1 (pattern of 5:
//      4 transpose + 1 gate) so gate blocks don't serialize ahead of the
//      w1 transpose (contiguous-range specialization = de-facto serial;
//      r13's homogeneous transpose_all ran both weights in ~85us).

#define T_TOK 4096
#define DM 1024
#define DF 4096
#define NE 8
#define BM 128              // M tile (pair rows)
#define BN 128              // N tile
#define BK 64               // K step
#define MAX_TILES 72        // sum ceil(c_e/128) <= 64 + 8
#define PAIR_CAP 9216       // MAX_TILES * 128
#define G1_GRID (MAX_TILES * 32)     // 2304 gemm1 work slots
#define TSTR 138            // transpose LDS stride (ushorts)

typedef __bf16 bf16x8 __attribute__((ext_vector_type(8)));
typedef float f32x4 __attribute__((ext_vector_type(4)));
typedef unsigned short ushort_t;

__device__ __forceinline__ ushort_t f2bf(float f) {
  uint32_t u = __float_as_uint(f);
  u += 0x7FFFu + ((u >> 16) & 1u);   // RNE
  return (ushort_t)(u >> 16);
}

// ---- workspace layout (bytes) ----
#define W1T_OFF 0ull                 // [E][DF][DM] bf16 = 64MiB
#define W2T_OFF 67108864ull          // [E][DM][DF] bf16 = 64MiB
#define XB_OFF  134217728ull         // [T][DM] bf16 = 8MiB
#define H_OFF   142606336ull         // [PAIR_CAP][DF] bf16 = 72MiB
#define RT_OFF  218103808ull         // routing block
#define RO_COUNTS   0
#define RO_NTILES   96
#define RO_TILE_E   128              // 288B
#define RO_TILE_S   448              // 288B
#define RO_TILE_R   768              // 288B
#define RO_PTOK     1088             // 36864B
#define RO_PW       37952            // 36864B
#define RO_TOPI     74816            // 32768B
#define RO_TOPW     107584           // 32768B
#define RT_BYTES    140352ull
#define WS_NEEDED   (RT_OFF + RT_BYTES)

// Runtime-balanced XCD-chunked mapping (XCD of block b = b%8).
__device__ __forceinline__ int xcd_work(int b, int live) {
  int k = b & 7, j = b >> 3;
  int q = live >> 3, r = live & 7;
  int cnt = q + (k < r ? 1 : 0);
  if (j >= cnt) return -1;
  int start = k * q + (k < r ? k : r);
  return start + j;
}

// ------------------------------------------------------------------
// shared transpose body: one 128r x 64c fp32 tile -> bf16 [C][R]
// ------------------------------------------------------------------
__device__ __forceinline__ void transpose_tile(
    ushort_t* sh, const float* __restrict__ src, ushort_t* __restrict__ dst,
    int R, int C, int bx, int by, int e) {
  src += (size_t)e * R * C;
  dst += (size_t)e * R * C;
  int c0 = bx * 64, r0 = by * 128;
  int tr = threadIdx.x >> 4;          // 0..15
  int tc = (threadIdx.x & 15) << 2;   // 0..60
#pragma unroll
  for (int i = 0; i < 8; ++i) {
    int r = i * 16 + tr;
    float4 v = *(const float4*)&src[(size_t)(r0 + r) * C + c0 + tc];
    sh[(tc + 0) * TSTR + r] = f2bf(v.x);
    sh[(tc + 1) * TSTR + r] = f2bf(v.y);
    sh[(tc + 2) * TSTR + r] = f2bf(v.z);
    sh[(tc + 3) * TSTR + r] = f2bf(v.w);
  }
  __syncthreads();
  int cr = threadIdx.x >> 5;          // 0..7
  int rg = (threadIdx.x & 31) << 2;   // 0..124
#pragma unroll
  for (int j = 0; j < 8; ++j) {
    int c = j * 8 + cr;
    ushort4 o = { sh[c * TSTR + rg], sh[c * TSTR + rg + 1],
                  sh[c * TSTR + rg + 2], sh[c * TSTR + rg + 3] };
    *(ushort4*)&dst[(size_t)(c0 + c) * R + r0 + rg] = o;
  }
}

// ------------------------------------------------------------------
// 1. Fused + INTERLEAVED: grid 5120 = 1024 gate + 4096 w1-transpose,
//    pattern of 5 (b%5==4 -> gate b/5; else transpose (b/5)*4 + b%5).
// ------------------------------------------------------------------
__global__ __launch_bounds__(256) void gate_w1t_kernel(
    const float* __restrict__ x, const float* __restrict__ gw,
    int* __restrict__ counts, int* __restrict__ topi,
    float* __restrict__ topw, ushort_t* __restrict__ xb,
    const float* __restrict__ w1, ushort_t* __restrict__ w1t) {
  __shared__ ushort_t sh[64 * TSTR];
  int b = blockIdx.x;
  int q5 = b / 5, r5 = b - q5 * 5;
  if (r5 != 4) {
    int t = q5 * 4 + r5;              // 0..4095: e(8) x by(8) x bx(64)
    int e = t >> 9, t2 = t & 511;
    transpose_tile(sh, w1, w1t, DM, DF, t2 & 63, t2 >> 6, e);
    return;
  }
  int wave = threadIdx.x >> 6;
  int lane = threadIdx.x & 63;
  int t = q5 * 4 + wave;              // q5 in 0..1023
  const float* xr = x + (size_t)t * DM;
  ushort_t* xbr = xb + (size_t)t * DM;
  float acc[NE];
#pragma unroll
  for (int e = 0; e < NE; ++e) acc[e] = 0.f;
#pragma unroll
  for (int it = 0; it < DM / 256; ++it) {
    int d0 = (it * 64 + lane) * 4;
    float4 v = *(const float4*)&xr[d0];
    ushort4 o = { f2bf(v.x), f2bf(v.y), f2bf(v.z), f2bf(v.w) };
    *(ushort4*)&xbr[d0] = o;
    const float* g0 = gw + (size_t)d0 * NE;
#pragma unroll
    for (int e = 0; e < NE; ++e)
      acc[e] += v.x * g0[e] + v.y * g0[NE + e] + v.z * g0[2 * NE + e] + v.w * g0[3 * NE + e];
  }
#pragma unroll
  for (int off = 32; off > 0; off >>= 1) {
#pragma unroll
    for (int e = 0; e < NE; ++e) acc[e] += __shfl_xor(acc[e], off, 64);
  }
  if (lane == 0) {
    int i0 = 0; float v0 = acc[0];
#pragma unroll
    for (int e = 1; e < NE; ++e) if (acc[e] > v0) { v0 = acc[e]; i0 = e; }
    int i1 = -1; float v1 = -1e30f;
#pragma unroll
    for (int e = 0; e < NE; ++e) if (e != i0 && acc[e] > v1) { v1 = acc[e]; i1 = e; }
    float e1 = expf(v1 - v0);
    float w0 = 1.f / (1.f + e1);
    float w1s = e1 / (1.f + e1);
    topi[t * 2] = i0; topi[t * 2 + 1] = i1;
    topw[t * 2] = w0; topw[t * 2 + 1] = w1s;
    atomicAdd(&counts[i0], 1);
    atomicAdd(&counts[i1], 1);
  }
}

// ------------------------------------------------------------------
// 2. Route: scan (thread 0) + parallel scatter, one block, LDS cursors
// ------------------------------------------------------------------
__global__ void route_kernel(const int* __restrict__ counts,
                             const int* __restrict__ topi, const float* __restrict__ topw,
                             int* __restrict__ n_tiles, int* __restrict__ tile_e,
                             int* __restrict__ tile_s, int* __restrict__ tile_r,
                             int* __restrict__ ptok, float* __restrict__ pw) {
  __shared__ int loff[NE];
  __shared__ int lcur[NE];
  if (threadIdx.x == 0) {
    int off = 0, nt = 0;
    for (int e = 0; e < NE; ++e) {
      loff[e] = off;
      lcur[e] = 0;
      int c = counts[e];
      for (int m0 = 0; m0 < c; m0 += BM) {
        tile_e[nt] = e;
        tile_s[nt] = off + m0;
        tile_r[nt] = (c - m0 < BM) ? (c - m0) : BM;
        ++nt;
      }
      off += ((c + BM - 1) / BM) * BM;
    }
    *n_tiles = nt;
  }
  __syncthreads();
  for (int t = threadIdx.x; t < T_TOK; t += 256) {
#pragma unroll
    for (int k = 0; k < 2; ++k) {
      int e = topi[t * 2 + k];
      int pos = atomicAdd(&lcur[e], 1);
      int p = loff[e] + pos;
      ptok[p] = t;
      pw[p] = topw[t * 2 + k];
    }
  }
}

// ==================================================================
// m97-replica 128x128xBK64 grouped-GEMM core (unchanged).
// ==================================================================

#define GLD(srcp, dstp)                                                        \
  __builtin_amdgcn_global_load_lds(                                            \
      (const __attribute__((address_space(1))) void*)(srcp),                   \
      (__attribute__((address_space(3))) void*)(dstp), 16, 0, 0)

__device__ __forceinline__ void gemm_core(
    ushort_t* As, ushort_t* Bs,
    const ushort_t* const (&a_sp)[4], const ushort_t* const (&b_sp)[4],
    int NT, int wid, int lane, f32x4 (&acc)[4][4]) {
  int fr = lane & 15, ch = lane >> 4, sw = lane & 7;
  int k0s = (ch ^ sw) * 8;
  int k1s = ((ch + 4) ^ sw) * 8;
  int m_off = (wid >> 1) * 64, n_off = (wid & 1) * 64;
  int abase = (m_off + fr) * 64;
  int bbase = (n_off + fr) * 64;

  for (int t = 0; t < NT; ++t) {
    int k0 = t * BK;
#pragma unroll
    for (int j = 0; j < 4; ++j) {
      GLD(a_sp[j] + k0, As + (wid * 4 + j) * 512);
      GLD(b_sp[j] + k0, Bs + (wid * 4 + j) * 512);
    }
    asm volatile("s_waitcnt vmcnt(0)" ::: "memory");
    __syncthreads();

#pragma unroll
    for (int kx = 0; kx < 2; ++kx) {
      int ks = kx ? k1s : k0s;
      bf16x8 af[4], bf[4];
#pragma unroll
      for (int mi = 0; mi < 4; ++mi) af[mi] = *(const bf16x8*)&As[abase + mi * 1024 + ks];
#pragma unroll
      for (int ni = 0; ni < 4; ++ni) bf[ni] = *(const bf16x8*)&Bs[bbase + ni * 1024 + ks];
#pragma unroll
      for (int mi = 0; mi < 4; ++mi)
#pragma unroll
        for (int ni = 0; ni < 4; ++ni)
          acc[mi][ni] = __builtin_amdgcn_mfma_f32_16x16x32_bf16(af[mi], bf[ni], acc[mi][ni], 0, 0, 0);
    }
    __syncthreads();
  }
}

// ------------------------------------------------------------------
// 3. Fused: gemm1 blocks [0,G1_GRID) ∥ w2-transpose blocks [G1_GRID,+4096)
//    (gemm1 blocks are long-lived; w2t hides in their shadow — kept as r17).
// ------------------------------------------------------------------
__global__ __launch_bounds__(256, 4) void gemm1_w2t_kernel(
    const ushort_t* __restrict__ xb, const ushort_t* __restrict__ w1t,
    ushort_t* __restrict__ h,
    const int* __restrict__ n_tiles, const int* __restrict__ tile_e,
    const int* __restrict__ tile_s, const int* __restrict__ tile_r,
    const int* __restrict__ ptok,
    const float* __restrict__ w2, ushort_t* __restrict__ w2t) {
  __shared__ ushort_t sh[BM * BK + BN * BK];   // 32 KiB; transpose uses 64*138
  int b = blockIdx.x;
  if (b >= G1_GRID) {
    int t = b - G1_GRID;              // 4096 blocks: e(8) x by(32) x bx(16)
    int e = t >> 9, t2 = t & 511;
    transpose_tile(sh, w2, w2t, DF, DM, t2 & 15, t2 >> 4, e);
    return;
  }
  int nt = *n_tiles;
  int ntp = (nt + 3) & ~3;
  int w = xcd_work(b, ntp * 32);
  if (w < 0) return;
  int g = w >> 5, r = w & 31;
  int tg = g >> 2, ng = g & 3;
  int tile = tg * 4 + (r & 3);
  if (tile >= nt) return;
  int n0 = (ng * 8 + (r >> 2)) * BN;
  int e = tile_e[tile], p0 = tile_s[tile], rows = tile_r[tile];

  ushort_t* As = sh;
  ushort_t* Bs = sh + BM * BK;
  int tid = threadIdx.x, wid = tid >> 6, lane = tid & 63;
  int lr = lane >> 3;
  int swc = (lane & 7) ^ (lr & 7);

  const ushort_t* a_sp[4];
  const ushort_t* b_sp[4];
#pragma unroll
  for (int j = 0; j < 4; ++j) {
    int rr = wid * 32 + j * 8 + lr;
    int tok = (rr < rows) ? ptok[p0 + rr] : 0;
    a_sp[j] = xb + (size_t)tok * DM + swc * 8;
    b_sp[j] = w1t + ((size_t)e * DF + n0 + rr) * DM + swc * 8;
  }

  f32x4 acc[4][4] = {};
  gemm_core(As, Bs, a_sp, b_sp, DM / BK, wid, lane, acc);

  int m_off = (wid >> 1) * 64, n_off = (wid & 1) * 64;
  int col = lane & 15, rq = (lane >> 4) * 4;
#pragma unroll
  for (int mi = 0; mi < 4; ++mi)
#pragma unroll
    for (int rr = 0; rr < 4; ++rr) {
      int m = m_off + mi * 16 + rq + rr;
      bool valid = m < rows;
      size_t rowoff = (size_t)(p0 + m) * DF + n0 + n_off;
#pragma unroll
      for (int ni = 0; ni < 4; ++ni) {
        float v = acc[mi][ni][rr];
        v = valid ? (v > 0.f ? v : 0.f) : 0.f;
        h[rowoff + ni * 16 + col] = f2bf(v);
      }
    }
}

// ------------------------------------------------------------------
// 4. GEMM2: out[tok(p)] += pw[p] * (h[p] @ W2_e)   (atomic epilogue,
//    2 commutative adds/element -> deterministic). Supertile 2x2.
// ------------------------------------------------------------------
__global__ __launch_bounds__(256, 4) void gemm2_kernel(
    const ushort_t* __restrict__ h, const ushort_t* __restrict__ w2t,
    float* __restrict__ out,
    const int* __restrict__ n_tiles, const int* __restrict__ tile_e,
    const int* __restrict__ tile_s, const int* __restrict__ tile_r,
    const int* __restrict__ ptok, const float* __restrict__ pw) {
  int nt = *n_tiles;
  int ntp = (nt + 1) & ~1;
  int w = xcd_work(blockIdx.x, ntp * 8);
  if (w < 0) return;
  int g = w >> 2, r = w & 3;
  int tg = g >> 2, ng = g & 3;
  int tile = tg * 2 + (r & 1);
  if (tile >= nt) return;
  int n0 = (ng * 2 + (r >> 1)) * BN;
  int e = tile_e[tile], p0 = tile_s[tile], rows = tile_r[tile];

  __shared__ ushort_t As[BM * BK];
  __shared__ ushort_t Bs[BN * BK];
  int tid = threadIdx.x, wid = tid >> 6, lane = tid & 63;
  int lr = lane >> 3;
  int swc = (lane & 7) ^ (lr & 7);

  const ushort_t* a_sp[4];
  const ushort_t* b_sp[4];
#pragma unroll
  for (int j = 0; j < 4; ++j) {
    int rr = wid * 32 + j * 8 + lr;
    a_sp[j] = h + (size_t)(p0 + rr) * DF + swc * 8;
    b_sp[j] = w2t + ((size_t)e * DM + n0 + rr) * DF + swc * 8;
  }

  f32x4 acc[4][4] = {};
  gemm_core(As, Bs, a_sp, b_sp, DF / BK, wid, lane, acc);

  int m_off = (wid >> 1) * 64, n_off = (wid & 1) * 64;
  int col = lane & 15, rq = (lane >> 4) * 4;
#pragma unroll
  for (int mi = 0; mi < 4; ++mi)
#pragma unroll
    for (int rr = 0; rr < 4; ++rr) {
      int m = m_off + mi * 16 + rq + rr;
      if (m < rows) {
        int p = p0 + m;
        int tok = ptok[p];
        float wgt = pw[p];
        size_t o = (size_t)tok * DM + n0 + n_off;
#pragma unroll
        for (int ni = 0; ni < 4; ++ni)
          atomicAdd(&out[o + ni * 16 + col], wgt * acc[mi][ni][rr]);
      }
    }
}

// ------------------------------------------------------------------
extern "C" void kernel_launch(void* const* d_in, const int* in_sizes, int n_in,
                              void* d_out, int out_size, void* d_ws, size_t ws_size,
                              hipStream_t stream) {
  const float* x  = (const float*)d_in[0];   // [2,2048,1024]
  const float* gw = (const float*)d_in[1];   // [1024,8]
  const float* w1 = (const float*)d_in[2];   // [8,1024,4096]
  const float* w2 = (const float*)d_in[3];   // [8,4096,1024]
  float* out = (float*)d_out;                // [4096,1024]
  char* ws = (char*)d_ws;
  if (ws_size < WS_NEEDED) return;

  ushort_t* w1t = (ushort_t*)(ws + W1T_OFF);
  ushort_t* w2t = (ushort_t*)(ws + W2T_OFF);
  ushort_t* xb  = (ushort_t*)(ws + XB_OFF);
  ushort_t* h   = (ushort_t*)(ws + H_OFF);
  char* rt = ws + RT_OFF;
  int*   counts  = (int*)(rt + RO_COUNTS);
  int*   n_tiles = (int*)(rt + RO_NTILES);
  int*   tile_e  = (int*)(rt + RO_TILE_E);
  int*   tile_s  = (int*)(rt + RO_TILE_S);
  int*   tile_r  = (int*)(rt + RO_TILE_R);
  int*   ptok    = (int*)(rt + RO_PTOK);
  float* pw      = (float*)(rt + RO_PW);
  int*   topi    = (int*)(rt + RO_TOPI);
  float* topw    = (float*)(rt + RO_TOPW);

  hipMemsetAsync(rt, 0, 128, stream);
  hipMemsetAsync(out, 0, (size_t)T_TOK * DM * sizeof(float), stream);

  hipLaunchKernelGGL(gate_w1t_kernel, dim3(5120), dim3(256), 0, stream,
                     x, gw, counts, topi, topw, xb, w1, w1t);
  hipLaunchKernelGGL(route_kernel, dim3(1), dim3(256), 0, stream,
                     counts, topi, topw, n_tiles, tile_e, tile_s, tile_r, ptok, pw);
  hipLaunchKernelGGL(gemm1_w2t_kernel, dim3(G1_GRID + 4096), dim3(256), 0, stream,
                     xb, w1t, h, n_tiles, tile_e, tile_s, tile_r, ptok, w2, w2t);
  hipLaunchKernelGGL(gemm2_kernel, dim3(MAX_TILES * 8), dim3(256), 0, stream,
                     h, w2t, out, n_tiles, tile_e, tile_s, tile_r, ptok, pw);
}

// Round 21
// 340.035 us; speedup vs baseline: 1.0903x; 1.0531x over previous
//
#include <hip/hip_runtime.h>
#include <hip/hip_bf16.h>
#include <stdint.h>

// MoE: T=4096 tokens, D_MODEL=1024, D_FF=4096, E=8, top-2.
// R21: r20 (best 358.1us) + XCD-preserving interleave of k3 (runs of 8
//      blocks, pattern of 25 runs: 9 gemm1 + 16 w2t-transpose; idx%8==b%8
//      so xcd_work/supertile grouping is unchanged).

#define T_TOK 4096
#define DM 1024
#define DF 4096
#define NE 8
#define BM 128              // M tile (pair rows)
#define BN 128              // N tile
#define BK 64               // K step
#define MAX_TILES 72        // sum ceil(c_e/128) <= 64 + 8
#define PAIR_CAP 9216       // MAX_TILES * 128
#define G1_GRID (MAX_TILES * 32)     // 2304 gemm1 work slots
#define TSTR 138            // transpose LDS stride (ushorts)

typedef __bf16 bf16x8 __attribute__((ext_vector_type(8)));
typedef float f32x4 __attribute__((ext_vector_type(4)));
typedef unsigned short ushort_t;

__device__ __forceinline__ ushort_t f2bf(float f) {
  uint32_t u = __float_as_uint(f);
  u += 0x7FFFu + ((u >> 16) & 1u);   // RNE
  return (ushort_t)(u >> 16);
}

// ---- workspace layout (bytes) ----
#define W1T_OFF 0ull                 // [E][DF][DM] bf16 = 64MiB
#define W2T_OFF 67108864ull          // [E][DM][DF] bf16 = 64MiB
#define XB_OFF  134217728ull         // [T][DM] bf16 = 8MiB
#define H_OFF   142606336ull         // [PAIR_CAP][DF] bf16 = 72MiB
#define RT_OFF  218103808ull         // routing block
#define RO_COUNTS   0
#define RO_NTILES   96
#define RO_TILE_E   128              // 288B
#define RO_TILE_S   448              // 288B
#define RO_TILE_R   768              // 288B
#define RO_PTOK     1088             // 36864B
#define RO_PW       37952            // 36864B
#define RO_TOPI     74816            // 32768B
#define RO_TOPW     107584           // 32768B
#define RT_BYTES    140352ull
#define WS_NEEDED   (RT_OFF + RT_BYTES)

// Runtime-balanced XCD-chunked mapping (XCD of block b = b%8).
__device__ __forceinline__ int xcd_work(int b, int live) {
  int k = b & 7, j = b >> 3;
  int q = live >> 3, r = live & 7;
  int cnt = q + (k < r ? 1 : 0);
  if (j >= cnt) return -1;
  int start = k * q + (k < r ? k : r);
  return start + j;
}

// ------------------------------------------------------------------
// shared transpose body: one 128r x 64c fp32 tile -> bf16 [C][R]
// ------------------------------------------------------------------
__device__ __forceinline__ void transpose_tile(
    ushort_t* sh, const float* __restrict__ src, ushort_t* __restrict__ dst,
    int R, int C, int bx, int by, int e) {
  src += (size_t)e * R * C;
  dst += (size_t)e * R * C;
  int c0 = bx * 64, r0 = by * 128;
  int tr = threadIdx.x >> 4;          // 0..15
  int tc = (threadIdx.x & 15) << 2;   // 0..60
#pragma unroll
  for (int i = 0; i < 8; ++i) {
    int r = i * 16 + tr;
    float4 v = *(const float4*)&src[(size_t)(r0 + r) * C + c0 + tc];
    sh[(tc + 0) * TSTR + r] = f2bf(v.x);
    sh[(tc + 1) * TSTR + r] = f2bf(v.y);
    sh[(tc + 2) * TSTR + r] = f2bf(v.z);
    sh[(tc + 3) * TSTR + r] = f2bf(v.w);
  }
  __syncthreads();
  int cr = threadIdx.x >> 5;          // 0..7
  int rg = (threadIdx.x & 31) << 2;   // 0..124
#pragma unroll
  for (int j = 0; j < 8; ++j) {
    int c = j * 8 + cr;
    ushort4 o = { sh[c * TSTR + rg], sh[c * TSTR + rg + 1],
                  sh[c * TSTR + rg + 2], sh[c * TSTR + rg + 3] };
    *(ushort4*)&dst[(size_t)(c0 + c) * R + r0 + rg] = o;
  }
}

// ------------------------------------------------------------------
// 1. Fused + interleaved: grid 5120 = 1024 gate + 4096 w1-transpose,
//    pattern of 5 (b%5==4 -> gate b/5; else transpose (b/5)*4 + b%5).
// ------------------------------------------------------------------
__global__ __launch_bounds__(256) void gate_w1t_kernel(
    const float* __restrict__ x, const float* __restrict__ gw,
    int* __restrict__ counts, int* __restrict__ topi,
    float* __restrict__ topw, ushort_t* __restrict__ xb,
    const float* __restrict__ w1, ushort_t* __restrict__ w1t) {
  __shared__ ushort_t sh[64 * TSTR];
  int b = blockIdx.x;
  int q5 = b / 5, r5 = b - q5 * 5;
  if (r5 != 4) {
    int t = q5 * 4 + r5;              // 0..4095: e(8) x by(8) x bx(64)
    int e = t >> 9, t2 = t & 511;
    transpose_tile(sh, w1, w1t, DM, DF, t2 & 63, t2 >> 6, e);
    return;
  }
  int wave = threadIdx.x >> 6;
  int lane = threadIdx.x & 63;
  int t = q5 * 4 + wave;              // q5 in 0..1023
  const float* xr = x + (size_t)t * DM;
  ushort_t* xbr = xb + (size_t)t * DM;
  float acc[NE];
#pragma unroll
  for (int e = 0; e < NE; ++e) acc[e] = 0.f;
#pragma unroll
  for (int it = 0; it < DM / 256; ++it) {
    int d0 = (it * 64 + lane) * 4;
    float4 v = *(const float4*)&xr[d0];
    ushort4 o = { f2bf(v.x), f2bf(v.y), f2bf(v.z), f2bf(v.w) };
    *(ushort4*)&xbr[d0] = o;
    const float* g0 = gw + (size_t)d0 * NE;
#pragma unroll
    for (int e = 0; e < NE; ++e)
      acc[e] += v.x * g0[e] + v.y * g0[NE + e] + v.z * g0[2 * NE + e] + v.w * g0[3 * NE + e];
  }
#pragma unroll
  for (int off = 32; off > 0; off >>= 1) {
#pragma unroll
    for (int e = 0; e < NE; ++e) acc[e] += __shfl_xor(acc[e], off, 64);
  }
  if (lane == 0) {
    int i0 = 0; float v0 = acc[0];
#pragma unroll
    for (int e = 1; e < NE; ++e) if (acc[e] > v0) { v0 = acc[e]; i0 = e; }
    int i1 = -1; float v1 = -1e30f;
#pragma unroll
    for (int e = 0; e < NE; ++e) if (e != i0 && acc[e] > v1) { v1 = acc[e]; i1 = e; }
    float e1 = expf(v1 - v0);
    float w0 = 1.f / (1.f + e1);
    float w1s = e1 / (1.f + e1);
    topi[t * 2] = i0; topi[t * 2 + 1] = i1;
    topw[t * 2] = w0; topw[t * 2 + 1] = w1s;
    atomicAdd(&counts[i0], 1);
    atomicAdd(&counts[i1], 1);
  }
}

// ------------------------------------------------------------------
// 2. Route: scan (thread 0) + parallel scatter, one block, LDS cursors
// ------------------------------------------------------------------
__global__ void route_kernel(const int* __restrict__ counts,
                             const int* __restrict__ topi, const float* __restrict__ topw,
                             int* __restrict__ n_tiles, int* __restrict__ tile_e,
                             int* __restrict__ tile_s, int* __restrict__ tile_r,
                             int* __restrict__ ptok, float* __restrict__ pw) {
  __shared__ int loff[NE];
  __shared__ int lcur[NE];
  if (threadIdx.x == 0) {
    int off = 0, nt = 0;
    for (int e = 0; e < NE; ++e) {
      loff[e] = off;
      lcur[e] = 0;
      int c = counts[e];
      for (int m0 = 0; m0 < c; m0 += BM) {
        tile_e[nt] = e;
        tile_s[nt] = off + m0;
        tile_r[nt] = (c - m0 < BM) ? (c - m0) : BM;
        ++nt;
      }
      off += ((c + BM - 1) / BM) * BM;
    }
    *n_tiles = nt;
  }
  __syncthreads();
  for (int t = threadIdx.x; t < T_TOK; t += 256) {
#pragma unroll
    for (int k = 0; k < 2; ++k) {
      int e = topi[t * 2 + k];
      int pos = atomicAdd(&lcur[e], 1);
      int p = loff[e] + pos;
      ptok[p] = t;
      pw[p] = topw[t * 2 + k];
    }
  }
}

// ==================================================================
// m97-replica 128x128xBK64 grouped-GEMM core (unchanged).
// ==================================================================

#define GLD(srcp, dstp)                                                        \
  __builtin_amdgcn_global_load_lds(                                            \
      (const __attribute__((address_space(1))) void*)(srcp),                   \
      (__attribute__((address_space(3))) void*)(dstp), 16, 0, 0)

__device__ __forceinline__ void gemm_core(
    ushort_t* As, ushort_t* Bs,
    const ushort_t* const (&a_sp)[4], const ushort_t* const (&b_sp)[4],
    int NT, int wid, int lane, f32x4 (&acc)[4][4]) {
  int fr = lane & 15, ch = lane >> 4, sw = lane & 7;
  int k0s = (ch ^ sw) * 8;
  int k1s = ((ch + 4) ^ sw) * 8;
  int m_off = (wid >> 1) * 64, n_off = (wid & 1) * 64;
  int abase = (m_off + fr) * 64;
  int bbase = (n_off + fr) * 64;

  for (int t = 0; t < NT; ++t) {
    int k0 = t * BK;
#pragma unroll
    for (int j = 0; j < 4; ++j) {
      GLD(a_sp[j] + k0, As + (wid * 4 + j) * 512);
      GLD(b_sp[j] + k0, Bs + (wid * 4 + j) * 512);
    }
    asm volatile("s_waitcnt vmcnt(0)" ::: "memory");
    __syncthreads();

#pragma unroll
    for (int kx = 0; kx < 2; ++kx) {
      int ks = kx ? k1s : k0s;
      bf16x8 af[4], bf[4];
#pragma unroll
      for (int mi = 0; mi < 4; ++mi) af[mi] = *(const bf16x8*)&As[abase + mi * 1024 + ks];
#pragma unroll
      for (int ni = 0; ni < 4; ++ni) bf[ni] = *(const bf16x8*)&Bs[bbase + ni * 1024 + ks];
#pragma unroll
      for (int mi = 0; mi < 4; ++mi)
#pragma unroll
        for (int ni = 0; ni < 4; ++ni)
          acc[mi][ni] = __builtin_amdgcn_mfma_f32_16x16x32_bf16(af[mi], bf[ni], acc[mi][ni], 0, 0, 0);
    }
    __syncthreads();
  }
}

// ------------------------------------------------------------------
// 3. Fused + XCD-preserving interleave: grid 6400 = 800 runs of 8.
//    Run pattern of 25: rr<9 -> gemm1 run (idx=(run/25*9+rr)*8+b%8),
//    else w2t-transpose run. idx%8 == b%8 so xcd_work is untouched.
// ------------------------------------------------------------------
__global__ __launch_bounds__(256, 4) void gemm1_w2t_kernel(
    const ushort_t* __restrict__ xb, const ushort_t* __restrict__ w1t,
    ushort_t* __restrict__ h,
    const int* __restrict__ n_tiles, const int* __restrict__ tile_e,
    const int* __restrict__ tile_s, const int* __restrict__ tile_r,
    const int* __restrict__ ptok,
    const float* __restrict__ w2, ushort_t* __restrict__ w2t) {
  __shared__ ushort_t sh[BM * BK + BN * BK];   // 32 KiB; transpose uses 64*138
  int b = blockIdx.x;
  int run = b >> 3, l8 = b & 7;
  int rg2 = run / 25, rr = run - rg2 * 25;
  if (rr >= 9) {
    int t = (rg2 * 16 + (rr - 9)) * 8 + l8;    // 0..4095: e(8) x by(32) x bx(16)
    int e = t >> 9, t2 = t & 511;
    transpose_tile(sh, w2, w2t, DF, DM, t2 & 15, t2 >> 4, e);
    return;
  }
  int bidx = (rg2 * 9 + rr) * 8 + l8;          // 0..2303, bidx%8 == b%8
  int nt = *n_tiles;
  int ntp = (nt + 3) & ~3;
  int w = xcd_work(bidx, ntp * 32);
  if (w < 0) return;
  int g = w >> 5, r = w & 31;
  int tg = g >> 2, ng = g & 3;
  int tile = tg * 4 + (r & 3);
  if (tile >= nt) return;
  int n0 = (ng * 8 + (r >> 2)) * BN;
  int e = tile_e[tile], p0 = tile_s[tile], rows = tile_r[tile];

  ushort_t* As = sh;
  ushort_t* Bs = sh + BM * BK;
  int tid = threadIdx.x, wid = tid >> 6, lane = tid & 63;
  int lr = lane >> 3;
  int swc = (lane & 7) ^ (lr & 7);

  const ushort_t* a_sp[4];
  const ushort_t* b_sp[4];
#pragma unroll
  for (int j = 0; j < 4; ++j) {
    int rr2 = wid * 32 + j * 8 + lr;
    int tok = (rr2 < rows) ? ptok[p0 + rr2] : 0;
    a_sp[j] = xb + (size_t)tok * DM + swc * 8;
    b_sp[j] = w1t + ((size_t)e * DF + n0 + rr2) * DM + swc * 8;
  }

  f32x4 acc[4][4] = {};
  gemm_core(As, Bs, a_sp, b_sp, DM / BK, wid, lane, acc);

  int m_off = (wid >> 1) * 64, n_off = (wid & 1) * 64;
  int col = lane & 15, rq = (lane >> 4) * 4;
#pragma unroll
  for (int mi = 0; mi < 4; ++mi)
#pragma unroll
    for (int rr2 = 0; rr2 < 4; ++rr2) {
      int m = m_off + mi * 16 + rq + rr2;
      bool valid = m < rows;
      size_t rowoff = (size_t)(p0 + m) * DF + n0 + n_off;
#pragma unroll
      for (int ni = 0; ni < 4; ++ni) {
        float v = acc[mi][ni][rr2];
        v = valid ? (v > 0.f ? v : 0.f) : 0.f;
        h[rowoff + ni * 16 + col] = f2bf(v);
      }
    }
}

// ------------------------------------------------------------------
// 4. GEMM2: out[tok(p)] += pw[p] * (h[p] @ W2_e)   (atomic epilogue,
//    2 commutative adds/element -> deterministic). Supertile 2x2.
// ------------------------------------------------------------------
__global__ __launch_bounds__(256, 4) void gemm2_kernel(
    const ushort_t* __restrict__ h, const ushort_t* __restrict__ w2t,
    float* __restrict__ out,
    const int* __restrict__ n_tiles, const int* __restrict__ tile_e,
    const int* __restrict__ tile_s, const int* __restrict__ tile_r,
    const int* __restrict__ ptok, const float* __restrict__ pw) {
  int nt = *n_tiles;
  int ntp = (nt + 1) & ~1;
  int w = xcd_work(blockIdx.x, ntp * 8);
  if (w < 0) return;
  int g = w >> 2, r = w & 3;
  int tg = g >> 2, ng = g & 3;
  int tile = tg * 2 + (r & 1);
  if (tile >= nt) return;
  int n0 = (ng * 2 + (r >> 1)) * BN;
  int e = tile_e[tile], p0 = tile_s[tile], rows = tile_r[tile];

  __shared__ ushort_t As[BM * BK];
  __shared__ ushort_t Bs[BN * BK];
  int tid = threadIdx.x, wid = tid >> 6, lane = tid & 63;
  int lr = lane >> 3;
  int swc = (lane & 7) ^ (lr & 7);

  const ushort_t* a_sp[4];
  const ushort_t* b_sp[4];
#pragma unroll
  for (int j = 0; j < 4; ++j) {
    int rr = wid * 32 + j * 8 + lr;
    a_sp[j] = h + (size_t)(p0 + rr) * DF + swc * 8;
    b_sp[j] = w2t + ((size_t)e * DM + n0 + rr) * DF + swc * 8;
  }

  f32x4 acc[4][4] = {};
  gemm_core(As, Bs, a_sp, b_sp, DF / BK, wid, lane, acc);

  int m_off = (wid >> 1) * 64, n_off = (wid & 1) * 64;
  int col = lane & 15, rq = (lane >> 4) * 4;
#pragma unroll
  for (int mi = 0; mi < 4; ++mi)
#pragma unroll
    for (int rr = 0; rr < 4; ++rr) {
      int m = m_off + mi * 16 + rq + rr;
      if (m < rows) {
        int p = p0 + m;
        int tok = ptok[p];
        float wgt = pw[p];
        size_t o = (size_t)tok * DM + n0 + n_off;
#pragma unroll
        for (int ni = 0; ni < 4; ++ni)
          atomicAdd(&out[o + ni * 16 + col], wgt * acc[mi][ni][rr]);
      }
    }
}

// ------------------------------------------------------------------
extern "C" void kernel_launch(void* const* d_in, const int* in_sizes, int n_in,
                              void* d_out, int out_size, void* d_ws, size_t ws_size,
                              hipStream_t stream) {
  const float* x  = (const float*)d_in[0];   // [2,2048,1024]
  const float* gw = (const float*)d_in[1];   // [1024,8]
  const float* w1 = (const float*)d_in[2];   // [8,1024,4096]
  const float* w2 = (const float*)d_in[3];   // [8,4096,1024]
  float* out = (float*)d_out;                // [4096,1024]
  char* ws = (char*)d_ws;
  if (ws_size < WS_NEEDED) return;

  ushort_t* w1t = (ushort_t*)(ws + W1T_OFF);
  ushort_t* w2t = (ushort_t*)(ws + W2T_OFF);
  ushort_t* xb  = (ushort_t*)(ws + XB_OFF);
  ushort_t* h   = (ushort_t*)(ws + H_OFF);
  char* rt = ws + RT_OFF;
  int*   counts  = (int*)(rt + RO_COUNTS);
  int*   n_tiles = (int*)(rt + RO_NTILES);
  int*   tile_e  = (int*)(rt + RO_TILE_E);
  int*   tile_s  = (int*)(rt + RO_TILE_S);
  int*   tile_r  = (int*)(rt + RO_TILE_R);
  int*   ptok    = (int*)(rt + RO_PTOK);
  float* pw      = (float*)(rt + RO_PW);
  int*   topi    = (int*)(rt + RO_TOPI);
  float* topw    = (float*)(rt + RO_TOPW);

  hipMemsetAsync(rt, 0, 128, stream);
  hipMemsetAsync(out, 0, (size_t)T_TOK * DM * sizeof(float), stream);

  hipLaunchKernelGGL(gate_w1t_kernel, dim3(5120), dim3(256), 0, stream,
                     x, gw, counts, topi, topw, xb, w1, w1t);
  hipLaunchKernelGGL(route_kernel, dim3(1), dim3(256), 0, stream,
                     counts, topi, topw, n_tiles, tile_e, tile_s, tile_r, ptok, pw);
  hipLaunchKernelGGL(gemm1_w2t_kernel, dim3(6400), dim3(256), 0, stream,
                     xb, w1t, h, n_tiles, tile_e, tile_s, tile_r, ptok, w2, w2t);
  hipLaunchKernelGGL(gemm2_kernel, dim3(MAX_TILES * 8), dim3(256), 0, stream,
                     h, w2t, out, n_tiles, tile_e, tile_s, tile_r, ptok, pw);
}